// Round 8
// baseline (28.569 us; speedup 1.0000x reference)
//
#include <hip/hip_runtime.h>
#include <hip/hip_fp16.h>
#include <math.h>

#define THREADS 64   // 1 wave/block, 2 box-pairs per thread (ILP-2)

__device__ __forceinline__ float prcp(float x) { return __builtin_amdgcn_rcpf(x); }

__device__ __forceinline__ unsigned packh2(float x, float y) {
    __half2 h = __floats2half2_rn(x, y);
    return *reinterpret_cast<unsigned*>(&h);
}
__device__ __forceinline__ void unpackh2(unsigned u, float& x, float& y) {
    __half2 h = *reinterpret_cast<__half2*>(&u);
    x = __low2float(h); y = __high2float(h);
}

__global__ void __launch_bounds__(THREADS) iou3d_kernel(
    const float* __restrict__ pred, const float* __restrict__ tgt,
    const float* __restrict__ wgt, float* __restrict__ partial, int N) {
    __shared__ unsigned ldsbuf[48 * THREADS];   // [stream*24+slot][tid] : bank = tid%32, conflict-free
    int tid = threadIdx.x;
#define LDSV(Q, S) ldsbuf[((((Q) * 24) + (S)) << 6) + tid]
    float loss = 0.0f;

    // persistent per-stream state
    float zov[2], volsum[2], wgtv[2], hw2a[2], hh2a[2];
    float fxa[2][4], fya[2][4];
    float pv[2][16];
    float sxa[2], sya[2];
    unsigned vma[2];
    int nva[2];
    unsigned ka0[24], ka1[24];

    // ---- phase A: load + geometry + in-box + intersections (per stream) ----
#pragma unroll
    for (int q = 0; q < 2; q++) {
        int n = blockIdx.x * (2 * THREADS) + tid + q * THREADS;
        bool live = n < N;
        int nc = live ? n : (N - 1);
        float p[7], t[7];
#pragma unroll
        for (int k = 0; k < 7; k++) {
            p[k] = pred[(size_t)nc * 7 + k];
            float tv = tgt[(size_t)nc * 7 + k];
            t[k] = (tv != tv) ? p[k] : tv;
        }
        wgtv[q] = live ? wgt[nc] : 0.0f;

        float zmax1 = p[2] + p[5] * 0.5f, zmin1 = p[2] - p[5] * 0.5f;
        float zmax2 = t[2] + t[5] * 0.5f, zmin2 = t[2] - t[5] * 0.5f;
        zov[q] = fmaxf(fminf(zmax1, zmax2) - fmaxf(zmin1, zmin2), 0.0f);
        volsum[q] = p[3] * p[4] * p[5] + t[3] * t[4] * t[5];

        float hw1 = 0.5f * p[3], hh1 = 0.5f * p[4];
        float hw2 = 0.5f * t[3], hh2 = 0.5f * t[4];
        hw2a[q] = hw2; hh2a[q] = hh2;
        float s1, c1v, s2, c2v;
        __sincosf(p[6], &s1, &c1v);
        __sincosf(t[6], &s2, &c2v);
        float c12 = c1v * c2v + s1 * s2;
        float s12 = s1 * c2v - c1v * s2;
        float ddx = p[0] - t[0], ddy = p[1] - t[1];
        float T12x =  c2v * ddx + s2 * ddy;
        float T12y = -s2 * ddx + c2v * ddy;
        float T21x = -(c1v * ddx + s1 * ddy);
        float T21y =  s1 * ddx - c1v * ddy;
        float ux = c12 * hw1, uy = s12 * hw1;
        float wx = -s12 * hh1, wy = c12 * hh1;
        float fx[4], fy[4];
        fx[0] = T12x + ux + wx; fy[0] = T12y + uy + wy;
        fx[1] = T12x - ux + wx; fy[1] = T12y - uy + wy;
        fx[2] = T12x - ux - wx; fy[2] = T12y - uy - wy;
        fx[3] = T12x + ux - wx; fy[3] = T12y + uy - wy;
#pragma unroll
        for (int k = 0; k < 4; k++) { fxa[q][k] = fx[k]; fya[q][k] = fy[k]; }

        unsigned vm = 0;
        float bx2 = hw2 * (1.0f + 2e-6f), by2 = hh2 * (1.0f + 2e-6f);
#pragma unroll
        for (int k = 0; k < 4; k++) {
            bool c = (fabsf(fx[k]) < bx2) && (fabsf(fy[k]) < by2);
            vm |= ((unsigned)c) << k;
        }
        float u2x = c12 * hw2, u2y = -s12 * hw2;
        float v2x = s12 * hh2, v2y = c12 * hh2;
        float bx1 = hw1 * (1.0f + 2e-6f), by1 = hh1 * (1.0f + 2e-6f);
        {
            float qx, qy;
            qx = T21x + u2x + v2x; qy = T21y + u2y + v2y;
            vm |= ((unsigned)((fabsf(qx) < bx1) && (fabsf(qy) < by1))) << 4;
            qx = T21x - u2x + v2x; qy = T21y - u2y + v2y;
            vm |= ((unsigned)((fabsf(qx) < bx1) && (fabsf(qy) < by1))) << 5;
            qx = T21x - u2x - v2x; qy = T21y - u2y - v2y;
            vm |= ((unsigned)((fabsf(qx) < bx1) && (fabsf(qy) < by1))) << 6;
            qx = T21x + u2x - v2x; qy = T21y + u2y - v2y;
            vm |= ((unsigned)((fabsf(qx) < bx1) && (fabsf(qy) < by1))) << 7;
        }
        float sx = 0.0f, sy = 0.0f;
#pragma unroll
        for (int k = 0; k < 4; k++) {
            LDSV(q, k) = packh2(fx[k], fy[k]);
            bool v = (vm >> k) & 1u;
            sx += v ? fx[k] : 0.0f; sy += v ? fy[k] : 0.0f;
        }
        LDSV(q, 4) = packh2(hw2, hh2);   LDSV(q, 5) = packh2(-hw2, hh2);
        LDSV(q, 6) = packh2(-hw2, -hh2); LDSV(q, 7) = packh2(hw2, -hh2);
        {
            bool v4 = (vm >> 4) & 1u, v5 = (vm >> 5) & 1u, v6 = (vm >> 6) & 1u, v7 = (vm >> 7) & 1u;
            sx += (v4 ? hw2 : 0.0f) + (v5 ? -hw2 : 0.0f) + (v6 ? -hw2 : 0.0f) + (v7 ? hw2 : 0.0f);
            sy += (v4 ? hh2 : 0.0f) + (v5 ? hh2 : 0.0f) + (v6 ? -hh2 : 0.0f) + (v7 ? -hh2 : 0.0f);
        }

        // intersections: exact reference-accepted set (u test collapsed to coordinate range test)
        float tux = ux + ux, tuy = uy + uy, twx = wx + wx, twy = wy + wy;
        float rtux = prcp(tux), rtuy = prcp(tuy), rtwx = prcp(twx), rtwy = prcp(twy);
        float dxe[4] = {-tux, -twx, tux, twx};
        float dye[4] = {-tuy, -twy, tuy, twy};
        float rdxe[4] = {-rtux, -rtwx, rtux, rtwx};
        float rdye[4] = {-rtuy, -rtwy, rtuy, rtwy};
        float w3 = 3.0f * hw2, h3 = 3.0f * hh2;
#pragma unroll
        for (int e1 = 0; e1 < 4; e1++) {
            float x1 = fx[e1], y1 = fy[e1];
            {   // e2=0: Y=+hh2 ; u in (0,1) <=> px in (hw2, 3hw2)
                float tt = (hh2 - y1) * rdye[e1];
                float px = fmaf(tt, dxe[e1], x1);
                bool mk = (tt > 0.0f) && (tt < 1.0f) && (px > hw2) && (px < w3);
                pv[q][e1 * 4 + 0] = px;
                float pxm = mk ? px : 0.0f, pym = mk ? hh2 : 0.0f;
                LDSV(q, 8 + e1 * 4 + 0) = packh2(pxm, pym);
                sx += pxm; sy += pym;
                vm |= ((unsigned)mk) << (8 + e1 * 4 + 0);
            }
            {   // e2=1: X=-hw2 ; u in (0,1) <=> py in (hh2, 3hh2)
                float tt = (-hw2 - x1) * rdxe[e1];
                float py = fmaf(tt, dye[e1], y1);
                bool mk = (tt > 0.0f) && (tt < 1.0f) && (py > hh2) && (py < h3);
                pv[q][e1 * 4 + 1] = py;
                float pxm = mk ? -hw2 : 0.0f, pym = mk ? py : 0.0f;
                LDSV(q, 8 + e1 * 4 + 1) = packh2(pxm, pym);
                sx += pxm; sy += pym;
                vm |= ((unsigned)mk) << (8 + e1 * 4 + 1);
            }
            {   // e2=2: Y=-hh2 ; u in (0,1) <=> px in (-3hw2, -hw2)
                float tt = (-hh2 - y1) * rdye[e1];
                float px = fmaf(tt, dxe[e1], x1);
                bool mk = (tt > 0.0f) && (tt < 1.0f) && (px < -hw2) && (px > -w3);
                pv[q][e1 * 4 + 2] = px;
                float pxm = mk ? px : 0.0f, pym = mk ? -hh2 : 0.0f;
                LDSV(q, 8 + e1 * 4 + 2) = packh2(pxm, pym);
                sx += pxm; sy += pym;
                vm |= ((unsigned)mk) << (8 + e1 * 4 + 2);
            }
            {   // e2=3: X=+hw2 ; u in (0,1) <=> py in (-3hh2, -hh2)
                float tt = (hw2 - x1) * rdxe[e1];
                float py = fmaf(tt, dye[e1], y1);
                bool mk = (tt > 0.0f) && (tt < 1.0f) && (py < -hh2) && (py > -h3);
                pv[q][e1 * 4 + 3] = py;
                float pxm = mk ? hw2 : 0.0f, pym = mk ? py : 0.0f;
                LDSV(q, 8 + e1 * 4 + 3) = packh2(pxm, pym);
                sx += pxm; sy += pym;
                vm |= ((unsigned)mk) << (8 + e1 * 4 + 3);
            }
        }
        vma[q] = vm; sxa[q] = sx; sya[q] = sy;
    }

    // ---- phase B: sort keys per stream ----
#define KEYBUILD(Q, KA) do { \
        unsigned vm = vma[Q]; \
        int nv = __popc(vm); nva[Q] = nv; \
        float r0 = prcp(fmaxf((float)nv, 1.0f)); \
        float mx = sxa[Q] * r0, my = sya[Q] * r0; \
        float hw2 = hw2a[Q], hh2 = hh2a[Q]; \
        float hpx = hw2 - mx, hmx = -hw2 - mx, hpy = hh2 - my, hmy = -hh2 - my; \
        MK(KA, 0, fxa[Q][0] - mx, fya[Q][0] - my); \
        MK(KA, 1, fxa[Q][1] - mx, fya[Q][1] - my); \
        MK(KA, 2, fxa[Q][2] - mx, fya[Q][2] - my); \
        MK(KA, 3, fxa[Q][3] - mx, fya[Q][3] - my); \
        MK(KA, 4, hpx, hpy); MK(KA, 5, hmx, hpy); MK(KA, 6, hmx, hmy); MK(KA, 7, hpx, hmy); \
        MK(KA, 8,  pv[Q][0] - mx, hpy);  MK(KA, 9,  hmx, pv[Q][1] - my); \
        MK(KA, 10, pv[Q][2] - mx, hmy);  MK(KA, 11, hpx, pv[Q][3] - my); \
        MK(KA, 12, pv[Q][4] - mx, hpy);  MK(KA, 13, hmx, pv[Q][5] - my); \
        MK(KA, 14, pv[Q][6] - mx, hmy);  MK(KA, 15, hpx, pv[Q][7] - my); \
        MK(KA, 16, pv[Q][8] - mx, hpy);  MK(KA, 17, hmx, pv[Q][9] - my); \
        MK(KA, 18, pv[Q][10] - mx, hmy); MK(KA, 19, hpx, pv[Q][11] - my); \
        MK(KA, 20, pv[Q][12] - mx, hpy); MK(KA, 21, hmx, pv[Q][13] - my); \
        MK(KA, 22, pv[Q][14] - mx, hmy); MK(KA, 23, hpx, pv[Q][15] - my); \
    } while (0)
#define MK(KA, K, XR, YR) do { \
        float xr_ = (XR), yr_ = (YR); \
        float d_ = fabsf(xr_) + fabsf(yr_); \
        float q_ = 1.0f - xr_ * prcp(d_); \
        float pa_ = copysignf(q_, yr_) + 4.0f; \
        unsigned key_ = (__float_as_uint(pa_) & 0xFFFFFFE0u) | (unsigned)(K); \
        KA[K] = ((vm >> (K)) & 1u) ? key_ : (0x7F000000u | (unsigned)(K)); \
    } while (0)
    KEYBUILD(0, ka0);
    KEYBUILD(1, ka1);
#undef MK
#undef KEYBUILD

    // ---- phase C: Batcher odd-even mergesort n=24 (132 CEs), both streams interleaved ----
#define CE1(KA, A, B) { unsigned lo_ = KA[A] < KA[B] ? KA[A] : KA[B]; \
                        unsigned hi_ = KA[A] < KA[B] ? KA[B] : KA[A]; \
                        KA[A] = lo_; KA[B] = hi_; }
#define CE(A, B) CE1(ka0, A, B) CE1(ka1, A, B)
    CE(0,1); CE(2,3); CE(4,5); CE(6,7); CE(8,9); CE(10,11); CE(12,13); CE(14,15); CE(16,17); CE(18,19); CE(20,21); CE(22,23);
    CE(0,2); CE(1,3); CE(4,6); CE(5,7); CE(8,10); CE(9,11); CE(12,14); CE(13,15); CE(16,18); CE(17,19); CE(20,22); CE(21,23);
    CE(1,2); CE(5,6); CE(9,10); CE(13,14); CE(17,18); CE(21,22);
    CE(0,4); CE(1,5); CE(2,6); CE(3,7); CE(8,12); CE(9,13); CE(10,14); CE(11,15); CE(16,20); CE(17,21); CE(18,22); CE(19,23);
    CE(2,4); CE(3,5); CE(10,12); CE(11,13); CE(18,20); CE(19,21);
    CE(1,2); CE(3,4); CE(5,6); CE(9,10); CE(11,12); CE(13,14); CE(17,18); CE(19,20); CE(21,22);
    CE(0,8); CE(1,9); CE(2,10); CE(3,11); CE(4,12); CE(5,13); CE(6,14); CE(7,15);
    CE(4,8); CE(5,9); CE(6,10); CE(7,11);
    CE(2,4); CE(3,5); CE(6,8); CE(7,9); CE(10,12); CE(11,13); CE(18,20); CE(19,21);
    CE(1,2); CE(3,4); CE(5,6); CE(7,8); CE(9,10); CE(11,12); CE(13,14); CE(17,18); CE(19,20); CE(21,22);
    CE(0,16); CE(1,17); CE(2,18); CE(3,19); CE(4,20); CE(5,21); CE(6,22); CE(7,23);
    CE(8,16); CE(9,17); CE(10,18); CE(11,19); CE(12,20); CE(13,21); CE(14,22); CE(15,23);
    CE(4,8); CE(5,9); CE(6,10); CE(7,11); CE(12,16); CE(13,17); CE(14,18); CE(15,19);
    CE(2,4); CE(3,5); CE(6,8); CE(7,9); CE(10,12); CE(11,13); CE(14,16); CE(15,17); CE(18,20); CE(19,21);
    CE(1,2); CE(3,4); CE(5,6); CE(7,8); CE(9,10); CE(11,12); CE(13,14); CE(15,16); CE(17,18); CE(19,20); CE(21,22);
#undef CE
#undef CE1

    // ---- phase D: gather + cyclic shoelace + iou per stream ----
#define SHOELACE(Q, KA) do { \
        unsigned gu[24]; \
        _Pragma("unroll") \
        for (int i = 0; i < 24; i++) \
            gu[i] = ldsbuf[((((Q) * 24) + (KA[i] & 31u)) << 6) + tid]; \
        int nv = nva[Q]; \
        float g0x, g0y; unpackh2(gu[0], g0x, g0y); \
        float prevx = g0x, prevy = g0y, area2 = 0.0f; \
        _Pragma("unroll") \
        for (int i = 1; i < 24; i++) { \
            float xx, yy; unpackh2(gu[i], xx, yy); \
            bool c = i < nv; \
            float cxv = c ? xx : g0x; \
            float cyv = c ? yy : g0y; \
            area2 += prevx * cyv - cxv * prevy; \
            prevx = cxv; prevy = cyv; \
        } \
        area2 += prevx * g0y - g0x * prevy; \
        float inter2d = 0.5f * fabsf(area2); \
        float inter3d = inter2d * zov[Q]; \
        float uni = volsum[Q] - inter3d; \
        float iou = inter3d / uni; \
        loss += (1.0f - iou) * wgtv[Q]; \
    } while (0)
    SHOELACE(0, ka0);
    SHOELACE(1, ka1);
#undef SHOELACE
#undef LDSV

    // one wave per block: pure shuffle reduction
#pragma unroll
    for (int off = 32; off > 0; off >>= 1) loss += __shfl_down(loss, off, 64);
    if (threadIdx.x == 0) partial[blockIdx.x] = loss;
}

__global__ void __launch_bounds__(1024) reduce_kernel(const float* __restrict__ partial,
                                                      int nb, float* __restrict__ out, int N) {
    float s = 0.0f;
    for (int i = threadIdx.x; i < nb; i += 1024) s += partial[i];
#pragma unroll
    for (int off = 32; off > 0; off >>= 1) s += __shfl_down(s, off, 64);
    __shared__ float sm[16];
    int lane = threadIdx.x & 63, wv = threadIdx.x >> 6;
    if (lane == 0) sm[wv] = s;
    __syncthreads();
    if (threadIdx.x == 0) {
        float tot = 0.0f;
#pragma unroll
        for (int k = 0; k < 16; k++) tot += sm[k];
        out[0] = tot / (float)N;
    }
}

extern "C" void kernel_launch(void* const* d_in, const int* in_sizes, int n_in,
                              void* d_out, int out_size, void* d_ws, size_t ws_size,
                              hipStream_t stream) {
    const float* pred = (const float*)d_in[0];
    const float* tgt  = (const float*)d_in[1];
    const float* wgt  = (const float*)d_in[2];
    int N = in_sizes[2];
    int nb = (N + 2 * THREADS - 1) / (2 * THREADS);
    float* partial = (float*)d_ws;
    iou3d_kernel<<<nb, THREADS, 0, stream>>>(pred, tgt, wgt, partial, N);
    reduce_kernel<<<1, 1024, 0, stream>>>(partial, nb, (float*)d_out, N);
}